// Round 2
// baseline (6689.886 us; speedup 1.0000x reference)
//
#include <hip/hip_runtime.h>

#define NPTS 60000
#define C 128
#define K 32
#define FF 512
#define CO 128
#define H 8
#define DH 16
#define TILE 16
#define EPS 1e-5f

// ---- ws layout ----
// [0, WTOTAL) fp32 weights; then acc (768 f), flag (1 int + pad), coords (N*3 f),
// then 4 big buffers (Qh, Kf, Vf, Y) in fp32 or bf16 depending on ws_size.
constexpr int OFF_INPROJ_W = 0;          // 384*128
constexpr int OFF_INPROJ_B = 49152;      // 384
constexpr int OFF_OUT_W    = 49536;      // 16384
constexpr int OFF_OUT_B    = 65920;      // 128
constexpr int OFF_QPOS_W   = 66048;      // 384
constexpr int OFF_QPOS_B   = 66432;      // 128
constexpr int OFF_KPOS_W   = 66560;      // 384
constexpr int OFF_KPOS_B   = 66944;      // 128
constexpr int OFF_N1G      = 67072;      // 128
constexpr int OFF_N1B      = 67200;      // 128
constexpr int OFF_N2G      = 67328;      // 128
constexpr int OFF_N2B      = 67456;      // 128
constexpr int OFF_LIN1_W   = 67584;      // 65536
constexpr int OFF_LIN1_B   = 133120;     // 512
constexpr int OFF_LIN2_W   = 133632;     // 65536
constexpr int OFF_LIN2_B   = 199168;     // 128
constexpr int OFF_OUTL_W   = 199296;     // 16384
constexpr int OFF_OUTL_B   = 215680;     // 128
constexpr int OFF_BOG      = 215808;     // 128
constexpr int OFF_BOB      = 215936;     // 128
constexpr int WTOTAL       = 216064;

constexpr size_t BIG0 = 1587456;  // byte offset of big buffers (256-aligned)

__device__ __forceinline__ float bf2f(unsigned short s) {
    return __uint_as_float(((unsigned)s) << 16);
}
__device__ __forceinline__ unsigned short f2bf(float f) {
    unsigned u = __float_as_uint(f);
    u += 0x7fffu + ((u >> 16) & 1u);
    return (unsigned short)(u >> 16);
}

// storage-type polymorphic load/store
__device__ __forceinline__ float ldE(const float* p, long i) { return p[i]; }
__device__ __forceinline__ float ldE(const unsigned short* p, long i) { return bf2f(p[i]); }
__device__ __forceinline__ void stE(float* p, long i, float v) { p[i] = v; }
__device__ __forceinline__ void stE(unsigned short* p, long i, float v) { p[i] = f2bf(v); }

// flag-dependent raw-input load
__device__ __forceinline__ float ldF(const void* p, long i, int bf) {
    return bf ? bf2f(((const unsigned short*)p)[i]) : ((const float*)p)[i];
}

// ---- dtype probe: bf16 data -> ~100% sane exponents; fp32-as-ushort -> ~58% ----
__global__ __launch_bounds__(256) void k_detect(const unsigned short* __restrict__ f,
                                                int* __restrict__ flag) {
    __shared__ int cnt_s;
    if (threadIdx.x == 0) cnt_s = 0;
    __syncthreads();
    int sane = 0;
    for (int j = 0; j < 16; ++j) {
        unsigned short u = f[threadIdx.x * 16 + j];
        int e = (u >> 7) & 255;
        sane += (u == 0 || (e >= 100 && e <= 142)) ? 1 : 0;
    }
    atomicAdd(&cnt_s, sane);
    __syncthreads();
    if (threadIdx.x == 0) *flag = (cnt_s >= 3686) ? 1 : 0;  // 90% of 4096
}

struct WTab {
    const void* src[20];
    int beg[20];
    int end[20];
};

__global__ __launch_bounds__(256) void k_cvt_weights(WTab tab, float* __restrict__ ws,
                                                     const int* __restrict__ flagp) {
    int bf = *flagp;
    int gid = blockIdx.x * 256 + threadIdx.x;
    #pragma unroll
    for (int j = 0; j < 20; ++j) {
        if (gid >= tab.beg[j] && gid < tab.end[j]) {
            int off = gid - tab.beg[j];
            ws[gid] = bf ? bf2f(((const unsigned short*)tab.src[j])[off])
                         : ((const float*)tab.src[j])[off];
        }
    }
}

// Fused: coords, q = feat + relu(coords@qposT+b), Qh/Kf/Vf projections
template <typename T>
__global__ __launch_bounds__(256) void k_proj(
    const float* __restrict__ ws_w, const void* __restrict__ featv,
    const int* __restrict__ flagp, const int* __restrict__ indices,
    float* __restrict__ coords, T* __restrict__ Qh, T* __restrict__ Kf,
    T* __restrict__ Vf)
{
    __shared__ float sx[TILE][C];
    __shared__ float sq[TILE][C];
    __shared__ float scd[TILE][4];
    int t = threadIdx.x;
    int row0 = blockIdx.x * TILE;
    const int bf = *flagp;
    for (int i = t; i < TILE*C; i += 256)
        sx[i>>7][i&127] = ldF(featv, (long)row0*C + i, bf);
    if (t < TILE*3) {
        int r = t/3, j = t - r*3;
        int n = row0 + r;
        int srci = (j==0) ? 3 : (j==1 ? 2 : 1);
        float vs = (j==2) ? 0.2f : 0.1f;
        float mn = (j==2) ? -3.0f : -40.0f;
        float v = ((float)indices[n*4+srci] + 0.5f)*vs + mn;
        scd[r][j] = v;
        coords[n*3+j] = v;
    }
    __syncthreads();
    const float* qpw = ws_w + OFF_QPOS_W;
    const float* qpb = ws_w + OFF_QPOS_B;
    for (int i = t; i < TILE*C; i += 256) {
        int r = i>>7, c = i&127;
        float a = qpb[c] + scd[r][0]*qpw[c*3] + scd[r][1]*qpw[c*3+1] + scd[r][2]*qpw[c*3+2];
        sq[r][c] = sx[r][c] + fmaxf(a, 0.0f);
    }
    __syncthreads();
    const float* ipw = ws_w + OFF_INPROJ_W;
    const float* ipb = ws_w + OFF_INPROJ_B;
    for (int i = t; i < TILE*C; i += 256) {
        int r = i>>7, o = i&127;
        const float4* wq = (const float4*)(ipw + o*C);
        const float4* wk = (const float4*)(ipw + (C+o)*C);
        const float4* wv = (const float4*)(ipw + (2*C+o)*C);
        const float4* xq = (const float4*)(&sq[r][0]);
        const float4* xx = (const float4*)(&sx[r][0]);
        float aq = ipb[o], ak = ipb[C+o], av = ipb[2*C+o];
        #pragma unroll 8
        for (int c4 = 0; c4 < C/4; ++c4) {
            float4 q4 = xq[c4], x4 = xx[c4];
            float4 a4 = wq[c4], b4 = wk[c4], v4 = wv[c4];
            aq += q4.x*a4.x + q4.y*a4.y + q4.z*a4.z + q4.w*a4.w;
            ak += x4.x*b4.x + x4.y*b4.y + x4.z*b4.z + x4.w*b4.w;
            av += x4.x*v4.x + x4.y*v4.y + x4.z*v4.z + x4.w*v4.w;
        }
        long g = (long)(row0+r)*C + o;
        stE(Qh, g, aq); stE(Kf, g, ak); stE(Vf, g, av);
    }
}

// One block per point: scores via Kf-gather + p contraction, softmax, att
template <typename T>
__global__ __launch_bounds__(256) void k_attn(
    const float* __restrict__ ws_w, const float* __restrict__ coords,
    const int* __restrict__ key_idx, const T* __restrict__ Qh,
    const T* __restrict__ Kf, const T* __restrict__ Vf, T* __restrict__ att)
{
    __shared__ float qh2[H][20];
    __shared__ float qkt[H][132];
    __shared__ float p_s[K][132];
    __shared__ float sc_s[H][33];
    __shared__ float s_hc[H][132];
    __shared__ float rel_s[K][3];
    __shared__ int   g_s[K];
    __shared__ float cn_s[3];
    int n = blockIdx.x;
    int t = threadIdx.x;
    if (t < C) qh2[t>>4][t&15] = ldE(Qh, (long)n*C + t);
    if (t >= 128 && t < 131) cn_s[t-128] = coords[n*3 + (t-128)];
    __syncthreads();
    if (t < K) {
        int g = key_idx[n*K + t];
        g_s[t] = g;
        int gc = g < 0 ? 0 : g;
        rel_s[t][0] = coords[gc*3+0] - cn_s[0];
        rel_s[t][1] = coords[gc*3+1] - cn_s[1];
        rel_s[t][2] = coords[gc*3+2] - cn_s[2];
    }
    const float* ipw = ws_w + OFF_INPROJ_W;
    // qkt[h][c] = sum_d qh[h][d] * wk[(C + h*DH + d)*C + c]
    for (int i = t; i < H*C; i += 256) {
        int h = i >> 7, c = i & 127;
        float acc = 0.f;
        const float* wkcol = ipw + (C + h*DH)*C + c;
        #pragma unroll
        for (int d = 0; d < DH; ++d)
            acc += qh2[h][d] * wkcol[d*C];
        qkt[h][c] = acc;
    }
    __syncthreads();
    const float* kpw = ws_w + OFF_KPOS_W;
    const float* kpb = ws_w + OFF_KPOS_B;
    for (int i = t; i < K*C; i += 256) {
        int k = i >> 7, c = i & 127;
        float a = kpb[c] + rel_s[k][0]*kpw[c*3] + rel_s[k][1]*kpw[c*3+1] + rel_s[k][2]*kpw[c*3+2];
        p_s[k][c] = fmaxf(a, 0.f);
    }
    __syncthreads();
    {
        int k = t >> 3, h = t & 7;
        int g = g_s[k];
        float score;
        if (g < 0) score = -1e30f;
        else {
            float acc = 0.f;
            long gb = (long)g*C + h*DH;
            #pragma unroll
            for (int d = 0; d < DH; ++d)
                acc += qh2[h][d] * ldE(Kf, gb + d);
            const float4* pp = (const float4*)(&p_s[k][0]);
            const float4* qq = (const float4*)(&qkt[h][0]);
            #pragma unroll 8
            for (int c4 = 0; c4 < C/4; ++c4) {
                float4 a4 = pp[c4], b4 = qq[c4];
                acc += a4.x*b4.x + a4.y*b4.y + a4.z*b4.z + a4.w*b4.w;
            }
            score = acc * 0.25f;   // 1/sqrt(DH)
        }
        sc_s[h][k] = score;
    }
    __syncthreads();
    {
        int k = t >> 3, h = t & 7;
        float m = -1e30f;
        for (int kk = 0; kk < K; ++kk) m = fmaxf(m, sc_s[h][kk]);
        float e = __expf(sc_s[h][k] - m);
        __syncthreads();
        sc_s[h][k] = e;
        __syncthreads();
        float s = 0.f;
        for (int kk = 0; kk < K; ++kk) s += sc_s[h][kk];
        float a = e / s;
        __syncthreads();
        sc_s[h][k] = a;
    }
    __syncthreads();
    for (int i = t; i < H*C; i += 256) {
        int h = i >> 7, c = i & 127;
        float acc = 0.f;
        #pragma unroll 8
        for (int k = 0; k < K; ++k)
            acc += sc_s[h][k] * p_s[k][c];
        s_hc[h][c] = acc;
    }
    __syncthreads();
    if (t < C) {
        int c = t, h = c >> 4;
        float a1 = 0.f;
        for (int k = 0; k < K; ++k) {
            int g = g_s[k]; int gc = g < 0 ? 0 : g;
            a1 += sc_s[h][k] * ldE(Vf, (long)gc*C + c);
        }
        float a2 = 0.f;
        const float4* wv4 = (const float4*)(ipw + (2*C + c)*C);
        const float4* sh4 = (const float4*)(&s_hc[h][0]);
        #pragma unroll 8
        for (int c4 = 0; c4 < C/4; ++c4) {
            float4 a4 = sh4[c4], b4 = wv4[c4];
            a2 += a4.x*b4.x + a4.y*b4.y + a4.z*b4.z + a4.w*b4.w;
        }
        stE(att, (long)n*C + c, a1 + a2);
    }
}

// y1 = feat + att@out_wT + out_b (in-place over att); stats -> acc1
template <typename T>
__global__ __launch_bounds__(256) void k_outproj(
    const float* __restrict__ ws_w, const void* __restrict__ featv,
    const int* __restrict__ flagp, T* __restrict__ Y, float* __restrict__ acc_s)
{
    __shared__ float sa[TILE][C];
    __shared__ float sy[TILE][C];
    int t = threadIdx.x;
    int row0 = blockIdx.x * TILE;
    const int bf = *flagp;
    for (int i = t; i < TILE*C; i += 256)
        sa[i>>7][i&127] = ldE(Y, (long)row0*C + i);
    __syncthreads();
    const float* ow = ws_w + OFF_OUT_W;
    const float* ob = ws_w + OFF_OUT_B;
    for (int i = t; i < TILE*C; i += 256) {
        int r = i>>7, j = i&127;
        float acc = ob[j];
        const float4* w4 = (const float4*)(ow + j*C);
        const float4* x4 = (const float4*)(&sa[r][0]);
        #pragma unroll 8
        for (int c4 = 0; c4 < C/4; ++c4) {
            float4 a4 = x4[c4], b4 = w4[c4];
            acc += a4.x*b4.x + a4.y*b4.y + a4.z*b4.z + a4.w*b4.w;
        }
        float y = ldF(featv, (long)row0*C + i, bf) + acc;
        sy[r][j] = y;
        stE(Y, (long)row0*C + i, y);
    }
    __syncthreads();
    if (t < C) {
        float s = 0.f, sq = 0.f;
        for (int r = 0; r < TILE; ++r) { float v = sy[r][t]; s += v; sq += v*v; }
        atomicAdd(&acc_s[t], s);
        atomicAdd(&acc_s[C + t], sq);
    }
}

// x1 = bn1(y1); y2 = x1 + ffn(x1) (in-place); stats -> acc2
template <typename T>
__global__ __launch_bounds__(256) void k_ffn(
    const float* __restrict__ ws_w, T* __restrict__ Y,
    const float* __restrict__ acc1, float* __restrict__ acc2)
{
    __shared__ float sx[TILE][C];
    __shared__ float sh[TILE][FF];
    __shared__ float sy[TILE][C];
    __shared__ float nsc[C], nsh[C];
    int t = threadIdx.x;
    int row0 = blockIdx.x * TILE;
    if (t < C) {
        float m = acc1[t] * (1.0f/NPTS);
        float v = acc1[C+t] * (1.0f/NPTS) - m*m;
        float rs = rsqrtf(v + EPS);
        float sc = rs * ws_w[OFF_N1G + t];
        nsc[t] = sc;
        nsh[t] = ws_w[OFF_N1B + t] - m * sc;
    }
    __syncthreads();
    for (int i = t; i < TILE*C; i += 256) {
        int c = i & 127;
        sx[i>>7][c] = ldE(Y, (long)row0*C + i) * nsc[c] + nsh[c];
    }
    __syncthreads();
    const float* l1w = ws_w + OFF_LIN1_W;
    const float* l1b = ws_w + OFF_LIN1_B;
    for (int i = t; i < TILE*FF; i += 256) {
        int r = i >> 9, f = i & 511;
        float acc = l1b[f];
        const float4* w4 = (const float4*)(l1w + f*C);
        const float4* x4 = (const float4*)(&sx[r][0]);
        #pragma unroll 8
        for (int c4 = 0; c4 < C/4; ++c4) {
            float4 a4 = x4[c4], b4 = w4[c4];
            acc += a4.x*b4.x + a4.y*b4.y + a4.z*b4.z + a4.w*b4.w;
        }
        sh[r][f] = fmaxf(acc, 0.f);
    }
    __syncthreads();
    const float* l2w = ws_w + OFF_LIN2_W;
    const float* l2b = ws_w + OFF_LIN2_B;
    for (int i = t; i < TILE*C; i += 256) {
        int r = i>>7, c = i&127;
        float acc = l2b[c];
        const float4* w4 = (const float4*)(l2w + c*FF);
        const float4* h4 = (const float4*)(&sh[r][0]);
        #pragma unroll 8
        for (int f4 = 0; f4 < FF/4; ++f4) {
            float4 a4 = h4[f4], b4 = w4[f4];
            acc += a4.x*b4.x + a4.y*b4.y + a4.z*b4.z + a4.w*b4.w;
        }
        float y = sx[r][c] + acc;
        sy[r][c] = y;
        stE(Y, (long)row0*C + i, y);
    }
    __syncthreads();
    if (t < C) {
        float s = 0.f, sq = 0.f;
        for (int r = 0; r < TILE; ++r) { float v = sy[r][t]; s += v; sq += v*v; }
        atomicAdd(&acc2[t], s);
        atomicAdd(&acc2[C+t], sq);
    }
}

// x2 = bn2(y2); y3 = x2@outlT + outl_b (in-place); stats -> acc3
template <typename T>
__global__ __launch_bounds__(256) void k_outl(
    const float* __restrict__ ws_w, T* __restrict__ Y,
    const float* __restrict__ acc2, float* __restrict__ acc3)
{
    __shared__ float sx[TILE][C];
    __shared__ float sy[TILE][CO];
    __shared__ float nsc[C], nsh[C];
    int t = threadIdx.x;
    int row0 = blockIdx.x * TILE;
    if (t < C) {
        float m = acc2[t] * (1.0f/NPTS);
        float v = acc2[C+t] * (1.0f/NPTS) - m*m;
        float rs = rsqrtf(v + EPS);
        float sc = rs * ws_w[OFF_N2G + t];
        nsc[t] = sc;
        nsh[t] = ws_w[OFF_N2B + t] - m * sc;
    }
    __syncthreads();
    for (int i = t; i < TILE*C; i += 256) {
        int c = i & 127;
        sx[i>>7][c] = ldE(Y, (long)row0*C + i) * nsc[c] + nsh[c];
    }
    __syncthreads();
    const float* w = ws_w + OFF_OUTL_W;
    const float* bb = ws_w + OFF_OUTL_B;
    for (int i = t; i < TILE*CO; i += 256) {
        int r = i>>7, o = i&127;
        float acc = bb[o];
        const float4* w4 = (const float4*)(w + o*C);
        const float4* x4 = (const float4*)(&sx[r][0]);
        #pragma unroll 8
        for (int c4 = 0; c4 < C/4; ++c4) {
            float4 a4 = x4[c4], b4 = w4[c4];
            acc += a4.x*b4.x + a4.y*b4.y + a4.z*b4.z + a4.w*b4.w;
        }
        sy[r][o] = acc;
        stE(Y, (long)row0*CO + i, acc);
    }
    __syncthreads();
    if (t < CO) {
        float s = 0.f, sq = 0.f;
        for (int r = 0; r < TILE; ++r) { float v = sy[r][t]; s += v; sq += v*v; }
        atomicAdd(&acc3[t], s);
        atomicAdd(&acc3[CO+t], sq);
    }
}

// out = relu(bn_out(y3)) -> output dtype per flag
template <typename T>
__global__ __launch_bounds__(256) void k_final(
    const float* __restrict__ ws_w, const T* __restrict__ Y,
    const float* __restrict__ acc3, const int* __restrict__ flagp,
    void* __restrict__ out)
{
    long i = (long)blockIdx.x * 256 + threadIdx.x;
    int c = (int)(i & (CO-1));
    float m = acc3[c] * (1.0f/NPTS);
    float v = acc3[CO+c] * (1.0f/NPTS) - m*m;
    float rs = rsqrtf(v + EPS);
    float y = (ldE(Y, i) - m) * rs * ws_w[OFF_BOG + c] + ws_w[OFF_BOB + c];
    y = fmaxf(y, 0.f);
    if (*flagp) ((unsigned short*)out)[i] = f2bf(y);
    else       ((float*)out)[i] = y;
}

extern "C" void kernel_launch(void* const* d_in, const int* in_sizes, int n_in,
                              void* d_out, int out_size, void* d_ws, size_t ws_size,
                              hipStream_t stream)
{
    char* base = (char*)d_ws;
    float* wsW = (float*)base;
    float* acc1 = wsW + WTOTAL;
    float* acc2 = acc1 + 256;
    float* acc3 = acc2 + 256;
    int* flagp = (int*)(wsW + WTOTAL + 768);
    float* coords = wsW + WTOTAL + 776;

    const void* featv = d_in[0];
    const int* indices = (const int*)d_in[1];
    const int* key_idx = (const int*)d_in[2];

    hipMemsetAsync(acc1, 0, 768 * sizeof(float), stream);
    k_detect<<<1, 256, 0, stream>>>((const unsigned short*)d_in[0], flagp);

    static const int cnt[20] = {49152,384,16384,128,384,128,384,128,128,128,
                                128,128,65536,512,65536,128,16384,128,128,128};
    WTab tab;
    int off = 0;
    for (int j = 0; j < 20; ++j) {
        tab.src[j] = d_in[3 + j];
        tab.beg[j] = off;
        tab.end[j] = off + cnt[j];
        off += cnt[j];
    }
    k_cvt_weights<<<WTOTAL/256, 256, 0, stream>>>(tab, wsW, flagp);

    size_t bigN = (size_t)NPTS * C;
    bool f32mode = (ws_size >= BIG0 + 4 * bigN * sizeof(float));

    if (f32mode) {
        float* Qh = (float*)(base + BIG0);
        float* Kf = Qh + bigN;
        float* Vf = Kf + bigN;
        float* Y  = Vf + bigN;
        k_proj<float><<<NPTS/TILE, 256, 0, stream>>>(wsW, featv, flagp, indices, coords, Qh, Kf, Vf);
        k_attn<float><<<NPTS, 256, 0, stream>>>(wsW, coords, key_idx, Qh, Kf, Vf, Y);
        k_outproj<float><<<NPTS/TILE, 256, 0, stream>>>(wsW, featv, flagp, Y, acc1);
        k_ffn<float><<<NPTS/TILE, 256, 0, stream>>>(wsW, Y, acc1, acc2);
        k_outl<float><<<NPTS/TILE, 256, 0, stream>>>(wsW, Y, acc2, acc3);
        k_final<float><<<(NPTS*CO)/256, 256, 0, stream>>>(wsW, Y, acc3, flagp, d_out);
    } else {
        unsigned short* Qh = (unsigned short*)(base + BIG0);
        unsigned short* Kf = Qh + bigN;
        unsigned short* Vf = Kf + bigN;
        unsigned short* Y  = Vf + bigN;
        k_proj<unsigned short><<<NPTS/TILE, 256, 0, stream>>>(wsW, featv, flagp, indices, coords, Qh, Kf, Vf);
        k_attn<unsigned short><<<NPTS, 256, 0, stream>>>(wsW, coords, key_idx, Qh, Kf, Vf, Y);
        k_outproj<unsigned short><<<NPTS/TILE, 256, 0, stream>>>(wsW, featv, flagp, Y, acc1);
        k_ffn<unsigned short><<<NPTS/TILE, 256, 0, stream>>>(wsW, Y, acc1, acc2);
        k_outl<unsigned short><<<NPTS/TILE, 256, 0, stream>>>(wsW, Y, acc2, acc3);
        k_final<unsigned short><<<(NPTS*CO)/256, 256, 0, stream>>>(wsW, Y, acc3, flagp, d_out);
    }
}

// Round 3
// 1258.915 us; speedup vs baseline: 5.3140x; 5.3140x over previous
//
#include <hip/hip_runtime.h>

#define NPTS 60000
#define C 128
#define K 32
#define FF 512
#define CO 128
#define H 8
#define DH 16
#define EPS 1e-5f

// ---- fp32 weight layout (float elements) ----
constexpr int OFF_INPROJ_W = 0;          // 384*128
constexpr int OFF_INPROJ_B = 49152;      // 384
constexpr int OFF_OUT_W    = 49536;      // 16384
constexpr int OFF_OUT_B    = 65920;      // 128
constexpr int OFF_QPOS_W   = 66048;      // 384
constexpr int OFF_QPOS_B   = 66432;      // 128
constexpr int OFF_KPOS_W   = 66560;      // 384
constexpr int OFF_KPOS_B   = 66944;      // 128
constexpr int OFF_N1G      = 67072;
constexpr int OFF_N1B      = 67200;
constexpr int OFF_N2G      = 67328;
constexpr int OFF_N2B      = 67456;
constexpr int OFF_LIN1_W   = 67584;      // 65536
constexpr int OFF_LIN1_B   = 133120;     // 512
constexpr int OFF_LIN2_W   = 133632;     // 65536
constexpr int OFF_LIN2_B   = 199168;     // 128
constexpr int OFF_OUTL_W   = 199296;     // 16384
constexpr int OFF_OUTL_B   = 215680;     // 128
constexpr int OFF_BOG      = 215808;
constexpr int OFF_BOB      = 215936;
constexpr int WTOTAL       = 216064;

// ---- bf16 weight copies (unsigned short elements, within wsB) ----
constexpr int B_INPROJ = 0;        // 384x128
constexpr int B_OUTW   = 49152;    // 128x128
constexpr int B_LIN1   = 65536;    // 512x128
constexpr int B_LIN2   = 131072;   // 128x512
constexpr int B_OUTL   = 196608;   // 128x128
constexpr size_t OFF_WB_BYTES  = 1587456;   // after fp32 weights+acc+flag+coords
constexpr size_t OFF_BIG_BYTES = 2013440;   // after 425984 B of bf16 weights

typedef __attribute__((ext_vector_type(8))) short bfrag8;
typedef __attribute__((ext_vector_type(4))) float f32x4;

__device__ __forceinline__ float bf2f(unsigned short s) {
    return __uint_as_float(((unsigned)s) << 16);
}
__device__ __forceinline__ unsigned short f2bf(float f) {
    unsigned u = __float_as_uint(f);
    u += 0x7fffu + ((u >> 16) & 1u);
    return (unsigned short)(u >> 16);
}
__device__ __forceinline__ float ldE(const float* p, long i) { return p[i]; }
__device__ __forceinline__ float ldE(const unsigned short* p, long i) { return bf2f(p[i]); }
__device__ __forceinline__ void stE(float* p, long i, float v) { p[i] = v; }
__device__ __forceinline__ void stE(unsigned short* p, long i, float v) { p[i] = f2bf(v); }
__device__ __forceinline__ float ldF(const void* p, long i, int bf) {
    return bf ? bf2f(((const unsigned short*)p)[i]) : ((const float*)p)[i];
}
// MFMA fragment load: row = lane&15 (m or n), k = k0 + (lane>>4)*8, 8 consecutive bf16
__device__ __forceinline__ bfrag8 ldfrag(const unsigned short* base, int stride, int lane, int k0) {
    return *(const bfrag8*)(base + (lane & 15) * stride + k0 + ((lane >> 4) << 3));
}

// ---- dtype probe ----
__global__ __launch_bounds__(256) void k_detect(const unsigned short* __restrict__ f,
                                                int* __restrict__ flag) {
    __shared__ int cnt_s;
    if (threadIdx.x == 0) cnt_s = 0;
    __syncthreads();
    int sane = 0;
    for (int j = 0; j < 16; ++j) {
        unsigned short u = f[threadIdx.x * 16 + j];
        int e = (u >> 7) & 255;
        sane += (u == 0 || (e >= 100 && e <= 142)) ? 1 : 0;
    }
    atomicAdd(&cnt_s, sane);
    __syncthreads();
    if (threadIdx.x == 0) *flag = (cnt_s >= 3686) ? 1 : 0;
}

struct WTab {
    const void* src[20];
    int beg[20];
    int end[20];
    int bo[20];   // bf16 copy dest offset in wsB, or -1
};

__global__ __launch_bounds__(256) void k_cvt_weights(WTab tab, float* __restrict__ ws,
                                                     unsigned short* __restrict__ wsB,
                                                     const int* __restrict__ flagp) {
    int bf = *flagp;
    int gid = blockIdx.x * 256 + threadIdx.x;
    #pragma unroll
    for (int j = 0; j < 20; ++j) {
        if (gid >= tab.beg[j] && gid < tab.end[j]) {
            int off = gid - tab.beg[j];
            float v;
            unsigned short raw;
            if (bf) { raw = ((const unsigned short*)tab.src[j])[off]; v = bf2f(raw); }
            else    { v = ((const float*)tab.src[j])[off]; raw = f2bf(v); }
            ws[gid] = v;
            if (tab.bo[j] >= 0) wsB[tab.bo[j] + off] = raw;
        }
    }
}

// ---- fused coords + qpos + QKV projection (MFMA) ----
template <typename T>
__global__ __launch_bounds__(256) void k_proj(
    const float* __restrict__ wsW, const unsigned short* __restrict__ wsB,
    const void* __restrict__ featv, const int* __restrict__ flagp,
    const int* __restrict__ indices, float* __restrict__ coords,
    T* __restrict__ Qh, T* __restrict__ Kf, T* __restrict__ Vf)
{
    __shared__ __align__(16) unsigned short sxb[32][136];
    __shared__ __align__(16) unsigned short sqb[32][136];
    __shared__ float scd[32][4];
    int t = threadIdx.x;
    int row0 = blockIdx.x * 32;
    const int bf = *flagp;
    if (t < 96) {
        int r = t / 3, j = t - 3 * r;
        int n = row0 + r;
        int srci = (j == 0) ? 3 : (j == 1 ? 2 : 1);
        float vs = (j == 2) ? 0.2f : 0.1f;
        float mn = (j == 2) ? -3.0f : -40.0f;
        float v = ((float)indices[n * 4 + srci] + 0.5f) * vs + mn;
        scd[r][j] = v;
        coords[n * 3 + j] = v;
    }
    __syncthreads();
    const float* qpw = wsW + OFF_QPOS_W;
    const float* qpb = wsW + OFF_QPOS_B;
    for (int i = t; i < 32 * C; i += 256) {
        int r = i >> 7, c = i & 127;
        float x = ldF(featv, (long)row0 * C + i, bf);
        float a = qpb[c] + scd[r][0]*qpw[c*3] + scd[r][1]*qpw[c*3+1] + scd[r][2]*qpw[c*3+2];
        sxb[r][c] = f2bf(x);
        sqb[r][c] = f2bf(x + fmaxf(a, 0.0f));
    }
    __syncthreads();
    int lane = t & 63, w = t >> 6;
    int col = lane & 15, quad = lane >> 4;
    // Q: 16 tiles (2m x 8n), rows 0..127 of in_proj
    for (int tid = w; tid < 16; tid += 4) {
        int mt = tid & 1, nt = tid >> 1, n0 = nt * 16;
        f32x4 acc = {0.f, 0.f, 0.f, 0.f};
        const unsigned short* aB = &sqb[mt*16][0];
        const unsigned short* bB = wsB + B_INPROJ + n0 * C;
        #pragma unroll
        for (int kt = 0; kt < 4; ++kt) {
            bfrag8 a = ldfrag(aB, 136, lane, kt*32);
            bfrag8 b = ldfrag(bB, C, lane, kt*32);
            acc = __builtin_amdgcn_mfma_f32_16x16x32_bf16(a, b, acc, 0, 0, 0);
        }
        #pragma unroll
        for (int r = 0; r < 4; ++r) {
            int m = row0 + mt*16 + quad*4 + r;
            int n = n0 + col;
            stE(Qh, (long)m * C + n, acc[r] + wsW[OFF_INPROJ_B + n]);
        }
    }
    // K,V: 32 tiles (2m x 16n), rows 128..383 of in_proj
    for (int tid = w; tid < 32; tid += 4) {
        int mt = tid & 1, nt = tid >> 1;
        int ng0 = 128 + nt * 16;
        f32x4 acc = {0.f, 0.f, 0.f, 0.f};
        const unsigned short* aB = &sxb[mt*16][0];
        const unsigned short* bB = wsB + B_INPROJ + ng0 * C;
        #pragma unroll
        for (int kt = 0; kt < 4; ++kt) {
            bfrag8 a = ldfrag(aB, 136, lane, kt*32);
            bfrag8 b = ldfrag(bB, C, lane, kt*32);
            acc = __builtin_amdgcn_mfma_f32_16x16x32_bf16(a, b, acc, 0, 0, 0);
        }
        #pragma unroll
        for (int r = 0; r < 4; ++r) {
            int m = row0 + mt*16 + quad*4 + r;
            int ng = ng0 + col;
            float v = acc[r] + wsW[OFF_INPROJ_B + ng];
            if (ng < 256) stE(Kf, (long)m * C + (ng - 128), v);
            else          stE(Vf, (long)m * C + (ng - 256), v);
        }
    }
}

// ---- attention (unchanged structure) ----
template <typename T>
__global__ __launch_bounds__(256) void k_attn(
    const float* __restrict__ ws_w, const float* __restrict__ coords,
    const int* __restrict__ key_idx, const T* __restrict__ Qh,
    const T* __restrict__ Kf, const T* __restrict__ Vf, T* __restrict__ att)
{
    __shared__ float qh2[H][20];
    __shared__ float qkt[H][132];
    __shared__ float p_s[K][132];
    __shared__ float sc_s[H][33];
    __shared__ float s_hc[H][132];
    __shared__ float rel_s[K][3];
    __shared__ int   g_s[K];
    __shared__ float cn_s[3];
    int n = blockIdx.x;
    int t = threadIdx.x;
    if (t < C) qh2[t>>4][t&15] = ldE(Qh, (long)n*C + t);
    if (t >= 128 && t < 131) cn_s[t-128] = coords[n*3 + (t-128)];
    __syncthreads();
    if (t < K) {
        int g = key_idx[n*K + t];
        g_s[t] = g;
        int gc = g < 0 ? 0 : g;
        rel_s[t][0] = coords[gc*3+0] - cn_s[0];
        rel_s[t][1] = coords[gc*3+1] - cn_s[1];
        rel_s[t][2] = coords[gc*3+2] - cn_s[2];
    }
    const float* ipw = ws_w + OFF_INPROJ_W;
    for (int i = t; i < H*C; i += 256) {
        int h = i >> 7, c = i & 127;
        float acc = 0.f;
        const float* wkcol = ipw + (C + h*DH)*C + c;
        #pragma unroll
        for (int d = 0; d < DH; ++d)
            acc += qh2[h][d] * wkcol[d*C];
        qkt[h][c] = acc;
    }
    __syncthreads();
    const float* kpw = ws_w + OFF_KPOS_W;
    const float* kpb = ws_w + OFF_KPOS_B;
    for (int i = t; i < K*C; i += 256) {
        int k = i >> 7, c = i & 127;
        float a = kpb[c] + rel_s[k][0]*kpw[c*3] + rel_s[k][1]*kpw[c*3+1] + rel_s[k][2]*kpw[c*3+2];
        p_s[k][c] = fmaxf(a, 0.f);
    }
    __syncthreads();
    {
        int k = t >> 3, h = t & 7;
        int g = g_s[k];
        float score;
        if (g < 0) score = -1e30f;
        else {
            float acc = 0.f;
            long gb = (long)g*C + h*DH;
            #pragma unroll
            for (int d = 0; d < DH; ++d)
                acc += qh2[h][d] * ldE(Kf, gb + d);
            const float4* pp = (const float4*)(&p_s[k][0]);
            const float4* qq = (const float4*)(&qkt[h][0]);
            #pragma unroll 8
            for (int c4 = 0; c4 < C/4; ++c4) {
                float4 a4 = pp[c4], b4 = qq[c4];
                acc += a4.x*b4.x + a4.y*b4.y + a4.z*b4.z + a4.w*b4.w;
            }
            score = acc * 0.25f;
        }
        sc_s[h][k] = score;
    }
    __syncthreads();
    {
        int k = t >> 3, h = t & 7;
        float m = -1e30f;
        for (int kk = 0; kk < K; ++kk) m = fmaxf(m, sc_s[h][kk]);
        float e = __expf(sc_s[h][k] - m);
        __syncthreads();
        sc_s[h][k] = e;
        __syncthreads();
        float s = 0.f;
        for (int kk = 0; kk < K; ++kk) s += sc_s[h][kk];
        float a = e / s;
        __syncthreads();
        sc_s[h][k] = a;
    }
    __syncthreads();
    for (int i = t; i < H*C; i += 256) {
        int h = i >> 7, c = i & 127;
        float acc = 0.f;
        #pragma unroll 8
        for (int k = 0; k < K; ++k)
            acc += sc_s[h][k] * p_s[k][c];
        s_hc[h][c] = acc;
    }
    __syncthreads();
    if (t < C) {
        int c = t, h = c >> 4;
        float a1 = 0.f;
        for (int k = 0; k < K; ++k) {
            int g = g_s[k]; int gc = g < 0 ? 0 : g;
            a1 += sc_s[h][k] * ldE(Vf, (long)gc*C + c);
        }
        float a2 = 0.f;
        const float4* wv4 = (const float4*)(ipw + (2*C + c)*C);
        const float4* sh4 = (const float4*)(&s_hc[h][0]);
        #pragma unroll 8
        for (int c4 = 0; c4 < C/4; ++c4) {
            float4 a4 = sh4[c4], b4 = wv4[c4];
            a2 += a4.x*b4.x + a4.y*b4.y + a4.z*b4.z + a4.w*b4.w;
        }
        stE(att, (long)n*C + c, a1 + a2);
    }
}

// ---- out-proj + residual + bn1 stats (MFMA) ----
template <typename T>
__global__ __launch_bounds__(256) void k_outproj(
    const float* __restrict__ wsW, const unsigned short* __restrict__ wsB,
    const void* __restrict__ featv, const int* __restrict__ flagp,
    T* __restrict__ Y, float* __restrict__ acc_s)
{
    __shared__ __align__(16) unsigned short sab[32][136];
    __shared__ float syf[32][132];
    int t = threadIdx.x;
    int row0 = blockIdx.x * 32;
    const int bf = *flagp;
    for (int i = t; i < 32 * C; i += 256)
        sab[i>>7][i&127] = f2bf(ldE(Y, (long)row0 * C + i));
    __syncthreads();
    int lane = t & 63, w = t >> 6;
    int col = lane & 15, quad = lane >> 4;
    for (int tid = w; tid < 16; tid += 4) {
        int mt = tid & 1, nt = tid >> 1, n0 = nt * 16;
        f32x4 acc = {0.f, 0.f, 0.f, 0.f};
        const unsigned short* aB = &sab[mt*16][0];
        const unsigned short* bB = wsB + B_OUTW + n0 * C;
        #pragma unroll
        for (int kt = 0; kt < 4; ++kt) {
            bfrag8 a = ldfrag(aB, 136, lane, kt*32);
            bfrag8 b = ldfrag(bB, C, lane, kt*32);
            acc = __builtin_amdgcn_mfma_f32_16x16x32_bf16(a, b, acc, 0, 0, 0);
        }
        #pragma unroll
        for (int r = 0; r < 4; ++r) {
            int m = mt*16 + quad*4 + r;
            int n = n0 + col;
            syf[m][n] = acc[r] + wsW[OFF_OUT_B + n] + ldF(featv, (long)(row0+m)*C + n, bf);
        }
    }
    __syncthreads();
    for (int i = t; i < 32 * C; i += 256)
        stE(Y, (long)row0 * C + i, syf[i>>7][i&127]);
    if (t < C) {
        float s = 0.f, sq = 0.f;
        for (int r = 0; r < 32; ++r) { float v = syf[r][t]; s += v; sq += v*v; }
        atomicAdd(&acc_s[t], s);
        atomicAdd(&acc_s[C + t], sq);
    }
}

// ---- bn1 + FFN + residual + bn2 stats (MFMA) ----
template <typename T>
__global__ __launch_bounds__(256) void k_ffn(
    const float* __restrict__ wsW, const unsigned short* __restrict__ wsB,
    T* __restrict__ Y, const float* __restrict__ acc1, float* __restrict__ acc2)
{
    __shared__ __align__(16) unsigned short sxb[32][136];
    __shared__ __align__(16) unsigned short sh[32][520];
    __shared__ float nsc[C], nsh[C];
    float (*syf)[132] = (float(*)[132])sh;   // aliased after GEMM2
    int t = threadIdx.x;
    int row0 = blockIdx.x * 32;
    if (t < C) {
        float m = acc1[t] * (1.0f/NPTS);
        float v = acc1[C+t] * (1.0f/NPTS) - m*m;
        float rs = rsqrtf(v + EPS);
        float sc = rs * wsW[OFF_N1G + t];
        nsc[t] = sc;
        nsh[t] = wsW[OFF_N1B + t] - m * sc;
    }
    __syncthreads();
    for (int i = t; i < 32 * C; i += 256) {
        int c = i & 127;
        sxb[i>>7][c] = f2bf(ldE(Y, (long)row0 * C + i) * nsc[c] + nsh[c]);
    }
    __syncthreads();
    int lane = t & 63, w = t >> 6;
    int col = lane & 15, quad = lane >> 4;
    // GEMM1: 32x128 @ lin1^T -> 32x512, relu -> sh
    for (int tid = w; tid < 64; tid += 4) {
        int mt = tid & 1, nt = tid >> 1, n0 = nt * 16;
        f32x4 acc = {0.f, 0.f, 0.f, 0.f};
        const unsigned short* aB = &sxb[mt*16][0];
        const unsigned short* bB = wsB + B_LIN1 + n0 * C;
        #pragma unroll
        for (int kt = 0; kt < 4; ++kt) {
            bfrag8 a = ldfrag(aB, 136, lane, kt*32);
            bfrag8 b = ldfrag(bB, C, lane, kt*32);
            acc = __builtin_amdgcn_mfma_f32_16x16x32_bf16(a, b, acc, 0, 0, 0);
        }
        #pragma unroll
        for (int r = 0; r < 4; ++r) {
            int m = mt*16 + quad*4 + r;
            int n = n0 + col;
            sh[m][n] = f2bf(fmaxf(acc[r] + wsW[OFF_LIN1_B + n], 0.f));
        }
    }
    __syncthreads();
    // GEMM2: 32x512 @ lin2^T -> 32x128, keep in regs (sh gets aliased)
    f32x4 accT[4];
    #pragma unroll
    for (int i = 0; i < 4; ++i) {
        int tid = w + 4*i;
        int mt = tid & 1, nt = tid >> 1, n0 = nt * 16;
        f32x4 acc = {0.f, 0.f, 0.f, 0.f};
        const unsigned short* aB = &sh[mt*16][0];
        const unsigned short* bB = wsB + B_LIN2 + n0 * FF;
        #pragma unroll
        for (int kt = 0; kt < 16; ++kt) {
            bfrag8 a = ldfrag(aB, 520, lane, kt*32);
            bfrag8 b = ldfrag(bB, FF, lane, kt*32);
            acc = __builtin_amdgcn_mfma_f32_16x16x32_bf16(a, b, acc, 0, 0, 0);
        }
        accT[i] = acc;
    }
    __syncthreads();
    #pragma unroll
    for (int i = 0; i < 4; ++i) {
        int tid = w + 4*i;
        int mt = tid & 1, nt = tid >> 1, n0 = nt * 16;
        #pragma unroll
        for (int r = 0; r < 4; ++r) {
            int m = mt*16 + quad*4 + r;
            int n = n0 + col;
            syf[m][n] = accT[i][r] + wsW[OFF_LIN2_B + n] + bf2f(sxb[m][n]);
        }
    }
    __syncthreads();
    for (int i = t; i < 32 * C; i += 256)
        stE(Y, (long)row0 * C + i, syf[i>>7][i&127]);
    if (t < C) {
        float s = 0.f, sq = 0.f;
        for (int r = 0; r < 32; ++r) { float v = syf[r][t]; s += v; sq += v*v; }
        atomicAdd(&acc2[t], s);
        atomicAdd(&acc2[C+t], sq);
    }
}

// ---- bn2 + output linear + bn3 stats (MFMA) ----
template <typename T>
__global__ __launch_bounds__(256) void k_outl(
    const float* __restrict__ wsW, const unsigned short* __restrict__ wsB,
    T* __restrict__ Y, const float* __restrict__ acc2, float* __restrict__ acc3)
{
    __shared__ __align__(16) unsigned short sxb[32][136];
    __shared__ float syf[32][132];
    __shared__ float nsc[C], nsh[C];
    int t = threadIdx.x;
    int row0 = blockIdx.x * 32;
    if (t < C) {
        float m = acc2[t] * (1.0f/NPTS);
        float v = acc2[C+t] * (1.0f/NPTS) - m*m;
        float rs = rsqrtf(v + EPS);
        float sc = rs * wsW[OFF_N2G + t];
        nsc[t] = sc;
        nsh[t] = wsW[OFF_N2B + t] - m * sc;
    }
    __syncthreads();
    for (int i = t; i < 32 * C; i += 256) {
        int c = i & 127;
        sxb[i>>7][c] = f2bf(ldE(Y, (long)row0 * C + i) * nsc[c] + nsh[c]);
    }
    __syncthreads();
    int lane = t & 63, w = t >> 6;
    int col = lane & 15, quad = lane >> 4;
    for (int tid = w; tid < 16; tid += 4) {
        int mt = tid & 1, nt = tid >> 1, n0 = nt * 16;
        f32x4 acc = {0.f, 0.f, 0.f, 0.f};
        const unsigned short* aB = &sxb[mt*16][0];
        const unsigned short* bB = wsB + B_OUTL + n0 * C;
        #pragma unroll
        for (int kt = 0; kt < 4; ++kt) {
            bfrag8 a = ldfrag(aB, 136, lane, kt*32);
            bfrag8 b = ldfrag(bB, C, lane, kt*32);
            acc = __builtin_amdgcn_mfma_f32_16x16x32_bf16(a, b, acc, 0, 0, 0);
        }
        #pragma unroll
        for (int r = 0; r < 4; ++r) {
            int m = mt*16 + quad*4 + r;
            int n = n0 + col;
            syf[m][n] = acc[r] + wsW[OFF_OUTL_B + n];
        }
    }
    __syncthreads();
    for (int i = t; i < 32 * CO; i += 256)
        stE(Y, (long)row0 * CO + i, syf[i>>7][i&127]);
    if (t < CO) {
        float s = 0.f, sq = 0.f;
        for (int r = 0; r < 32; ++r) { float v = syf[r][t]; s += v; sq += v*v; }
        atomicAdd(&acc3[t], s);
        atomicAdd(&acc3[CO+t], sq);
    }
}

// ---- final BN + relu -> output ----
template <typename T>
__global__ __launch_bounds__(256) void k_final(
    const float* __restrict__ wsW, const T* __restrict__ Y,
    const float* __restrict__ acc3, const int* __restrict__ flagp,
    void* __restrict__ out)
{
    long i = (long)blockIdx.x * 256 + threadIdx.x;
    int c = (int)(i & (CO-1));
    float m = acc3[c] * (1.0f/NPTS);
    float v = acc3[CO+c] * (1.0f/NPTS) - m*m;
    float rs = rsqrtf(v + EPS);
    float y = (ldE(Y, i) - m) * rs * wsW[OFF_BOG + c] + wsW[OFF_BOB + c];
    y = fmaxf(y, 0.f);
    if (*flagp) ((unsigned short*)out)[i] = f2bf(y);
    else        ((float*)out)[i] = y;
}

extern "C" void kernel_launch(void* const* d_in, const int* in_sizes, int n_in,
                              void* d_out, int out_size, void* d_ws, size_t ws_size,
                              hipStream_t stream)
{
    char* base = (char*)d_ws;
    float* wsW = (float*)base;
    float* acc1 = wsW + WTOTAL;
    float* acc2 = acc1 + 256;
    float* acc3 = acc2 + 256;
    int* flagp = (int*)(wsW + WTOTAL + 768);
    float* coords = wsW + WTOTAL + 776;
    unsigned short* wsB = (unsigned short*)(base + OFF_WB_BYTES);

    const void* featv = d_in[0];
    const int* indices = (const int*)d_in[1];
    const int* key_idx = (const int*)d_in[2];

    hipMemsetAsync(acc1, 0, 768 * sizeof(float), stream);
    k_detect<<<1, 256, 0, stream>>>((const unsigned short*)d_in[0], flagp);

    static const int cnt[20] = {49152,384,16384,128,384,128,384,128,128,128,
                                128,128,65536,512,65536,128,16384,128,128,128};
    static const int bofs[20] = {B_INPROJ,-1,B_OUTW,-1,-1,-1,-1,-1,-1,-1,
                                 -1,-1,B_LIN1,-1,B_LIN2,-1,B_OUTL,-1,-1,-1};
    WTab tab;
    int off = 0;
    for (int j = 0; j < 20; ++j) {
        tab.src[j] = d_in[3 + j];
        tab.beg[j] = off;
        tab.end[j] = off + cnt[j];
        tab.bo[j] = bofs[j];
        off += cnt[j];
    }
    k_cvt_weights<<<WTOTAL/256, 256, 0, stream>>>(tab, wsW, wsB, flagp);

    size_t bigN = (size_t)NPTS * C;
    bool f32mode = (ws_size >= OFF_BIG_BYTES + 4 * bigN * sizeof(float));

    if (f32mode) {
        float* Qh = (float*)(base + OFF_BIG_BYTES);
        float* Kf = Qh + bigN;
        float* Vf = Kf + bigN;
        float* Y  = Vf + bigN;
        k_proj<float><<<NPTS/32, 256, 0, stream>>>(wsW, wsB, featv, flagp, indices, coords, Qh, Kf, Vf);
        k_attn<float><<<NPTS, 256, 0, stream>>>(wsW, coords, key_idx, Qh, Kf, Vf, Y);
        k_outproj<float><<<NPTS/32, 256, 0, stream>>>(wsW, wsB, featv, flagp, Y, acc1);
        k_ffn<float><<<NPTS/32, 256, 0, stream>>>(wsW, wsB, Y, acc1, acc2);
        k_outl<float><<<NPTS/32, 256, 0, stream>>>(wsW, wsB, Y, acc2, acc3);
        k_final<float><<<(NPTS*CO)/256, 256, 0, stream>>>(wsW, Y, acc3, flagp, d_out);
    } else {
        unsigned short* Qh = (unsigned short*)(base + OFF_BIG_BYTES);
        unsigned short* Kf = Qh + bigN;
        unsigned short* Vf = Kf + bigN;
        unsigned short* Y  = Vf + bigN;
        k_proj<unsigned short><<<NPTS/32, 256, 0, stream>>>(wsW, wsB, featv, flagp, indices, coords, Qh, Kf, Vf);
        k_attn<unsigned short><<<NPTS, 256, 0, stream>>>(wsW, coords, key_idx, Qh, Kf, Vf, Y);
        k_outproj<unsigned short><<<NPTS/32, 256, 0, stream>>>(wsW, wsB, featv, flagp, Y, acc1);
        k_ffn<unsigned short><<<NPTS/32, 256, 0, stream>>>(wsW, wsB, Y, acc1, acc2);
        k_outl<unsigned short><<<NPTS/32, 256, 0, stream>>>(wsW, wsB, Y, acc2, acc3);
        k_final<unsigned short><<<(NPTS*CO)/256, 256, 0, stream>>>(wsW, Y, acc3, flagp, d_out);
    }
}